// Round 1
// baseline (3590.382 us; speedup 1.0000x reference)
//
#include <hip/hip_runtime.h>

// ---------------------------------------------------------------------------
// HeadPac forward: 14x 3x3 conv (5 PAC-modulated stages) + 4 PAC kernels, fp32.
// Layout NCHW everywhere. B=2. Spatial sizes 256/128/64/32/16 (all divide the
// 8x16 tile exactly -> no output bounds checks).
// ---------------------------------------------------------------------------

// ---------------- workspace layout (float offsets) ----------------
enum : size_t {
  OFF_A  = 0,          // 8,388,608 floats (33.5 MB)  ping buffer
  OFF_B  = 8388608,    // 4,194,304 floats (16.8 MB)  pong buffer
  OFF_P  = 12582912,   // 1,048,576 floats (4 MB)     conv c-split partial sums
  OFF_PK = 13631488,   //   294,912 floats (1.2 MB)   pac-kernel partial sums
  OFF_WT = 13926400,   // 21,971,520 floats (88 MB)   transposed weights
  WT_TOTAL = 21971520,
  WS_MIN_FLOATS  = 13926400,
  WS_FULL_FLOATS = 35897920,
};

// ---------------- d_out layout (float offsets), return order ----------------
enum : size_t {
  O_H1 = 0,          // [2,64,256,256]
  O_H2 = 8388608,    // [2,128,128,128]
  O_H3 = 12582912,   // [2,256,64,64]
  O_H4 = 14680064,   // [2,512,32,32]
  O_H5 = 15728640,   // [2,1024,16,16]
  O_K2 = 16252928,   // [2,9,128,128]
  O_K3 = 16547840,   // [2,9,64,64]
  O_K4 = 16621568,   // [2,9,32,32]
  O_K5 = 16640000,   // [2,9,16,16]
};

// ---------------------------------------------------------------------------
// Generic tiled 3x3 conv (pad=1), optional PAC kernel modulation, optional
// input-channel split (atomic partial sums, bias/relu deferred to epilogue).
// Block: 256 thr = 8 oc-groups x 32 px-groups. Tile: 64 oc x (8 rows x 16 cols).
// Per thread: 8 oc x 4 consecutive cols.
// Weights staged from transposed layout [Cin][9][Cout] (wmode=1) or original
// [Cout][Cin][3][3] (wmode=0, L1/L2-cached scattered reads).
// ---------------------------------------------------------------------------
template<int S, int HK, int SP, int KC>
__global__ __launch_bounds__(256) void conv3x3_k(
    const float* __restrict__ src, const float* __restrict__ wsrc, int wmode,
    const float* __restrict__ bias, const float* __restrict__ kern,
    float* __restrict__ dst, int Cin, int Cout, int H, int W, int CS)
{
  constexpr int TH = 8, TW = 16;
  constexpr int RH = TH * S + 2;        // staged input rows
  constexpr int RW = TW * S + 2;        // staged input cols
  constexpr int RWs = RW + 1;           // padded LDS stride
  constexpr int NX = 3 * S + 3;         // x values per (kc, di) per thread

  __shared__ float xs[KC][RH][RWs];
  __shared__ float wsm[KC][9][64];

  const int OH = H / S, OW = W / S;
  const int tid   = threadIdx.x;
  const int ocg   = tid >> 5;           // 0..7
  const int pxg   = tid & 31;           // 0..31
  const int prow  = pxg >> 2;           // 0..7
  const int pcol4 = (pxg & 3) << 2;     // 0,4,8,12
  const int tiles_w = OW / TW;
  const int tile  = blockIdx.x;
  const int th0   = (tile / tiles_w) * TH;
  const int tw0   = (tile % tiles_w) * TW;
  const int ocb   = blockIdx.y * 64;
  const int bz    = blockIdx.z;
  const int b     = bz / CS;
  const int cs    = bz - b * CS;
  const int CinS  = Cin / CS;
  const int c_base = cs * CinS;
  const int oh    = th0 + prow;
  const int ow0   = tw0 + pcol4;

  float acc[8][4];
#pragma unroll
  for (int o = 0; o < 8; ++o)
#pragma unroll
    for (int p = 0; p < 4; ++p) acc[o][p] = 0.f;

  // PAC factors: K[b][t][oh*S][ow*S], spatial dims = input H,W
  float kf[HK ? 9 : 1][4];
  if (HK) {
#pragma unroll
    for (int t = 0; t < 9; ++t)
#pragma unroll
      for (int p = 0; p < 4; ++p)
        kf[t][p] = kern[((size_t)(b * 9 + t) * H + (size_t)oh * S) * W
                        + (size_t)(ow0 + p) * S];
  }

  const float* xb = src + (size_t)b * Cin * H * W;

  for (int c0 = c_base; c0 < c_base + CinS; c0 += KC) {
    // ---- stage input tile ----
    for (int idx = tid; idx < KC * RH * RW; idx += 256) {
      int kc  = idx / (RH * RW);
      int rem = idx - kc * (RH * RW);
      int r   = rem / RW;
      int col = rem - r * RW;
      int ih = th0 * S + r - 1;
      int iw = tw0 * S + col - 1;
      float v = 0.f;
      if (ih >= 0 && ih < H && iw >= 0 && iw < W)
        v = xb[(size_t)(c0 + kc) * H * W + (size_t)ih * W + iw];
      xs[kc][r][col] = v;
    }
    // ---- stage weights ----
    for (int idx = tid; idx < KC * 9 * 64; idx += 256) {
      int kc  = idx / 576;
      int rem = idx - kc * 576;
      int t   = rem >> 6;
      int oc  = rem & 63;
      float wv;
      if (wmode)
        wv = wsrc[((size_t)(c0 + kc) * 9 + t) * Cout + ocb + oc];
      else
        wv = wsrc[((size_t)(ocb + oc) * Cin + (c0 + kc)) * 9 + t];
      wsm[kc][t][oc] = wv;
    }
    __syncthreads();

    // ---- FMA core ----
#pragma unroll
    for (int kc = 0; kc < KC; ++kc) {
#pragma unroll
      for (int di = 0; di < 3; ++di) {
        const float* xrow = &xs[kc][prow * S + di][pcol4 * S];
        float xv[NX];
#pragma unroll
        for (int q = 0; q < NX; ++q) xv[q] = xrow[q];
#pragma unroll
        for (int dj = 0; dj < 3; ++dj) {
          const int t = di * 3 + dj;
          float wv[8];
#pragma unroll
          for (int o = 0; o < 8; ++o) wv[o] = wsm[kc][t][ocg * 8 + o];
          float xq[4];
#pragma unroll
          for (int p = 0; p < 4; ++p) {
            float xvv = xv[S * p + dj];
            xq[p] = HK ? xvv * kf[t][p] : xvv;
          }
#pragma unroll
          for (int o = 0; o < 8; ++o)
#pragma unroll
            for (int p = 0; p < 4; ++p)
              acc[o][p] = fmaf(wv[o], xq[p], acc[o][p]);
        }
      }
    }
    __syncthreads();
  }

  // ---- writeback ----
#pragma unroll
  for (int o = 0; o < 8; ++o) {
    const int oc = ocb + ocg * 8 + o;
    float* orow = dst + ((size_t)b * Cout + oc) * OH * OW + (size_t)oh * OW + ow0;
    if (SP) {
#pragma unroll
      for (int p = 0; p < 4; ++p) atomicAdd(&orow[p], acc[o][p]);
    } else {
      const float bo = bias[oc];
#pragma unroll
      for (int p = 0; p < 4; ++p) orow[p] = fmaxf(acc[o][p] + bo, 0.f);
    }
  }
}

// ---------------------------------------------------------------------------
// PAC kernel stage 1: s[b][t][h][w] = sum_c (x[c, h+di-1, w+dj-1] - x[c,h,w])^2
// (zero padding; scale coeff^2 applied in stage 2). 16x16 px tile per block,
// optional channel split via atomics.
// ---------------------------------------------------------------------------
template<int KCC>
__global__ __launch_bounds__(256) void pac_s1(
    const float* __restrict__ g, float* __restrict__ s,
    int C, int H, int W, int CS)
{
  __shared__ float xs[KCC][18][19];
  const int tid = threadIdx.x;
  const int pr = tid >> 4, pc = tid & 15;
  const int tiles_w = W / 16;
  const int tile = blockIdx.x;
  const int th0 = (tile / tiles_w) * 16, tw0 = (tile % tiles_w) * 16;
  const int bz = blockIdx.y;
  const int b = bz / CS, cs = bz - b * CS;
  const int CinS = C / CS, c0b = cs * CinS;

  float acc[9];
#pragma unroll
  for (int t = 0; t < 9; ++t) acc[t] = 0.f;

  const float* gb = g + (size_t)b * C * H * W;
  for (int c0 = c0b; c0 < c0b + CinS; c0 += KCC) {
    for (int idx = tid; idx < KCC * 18 * 18; idx += 256) {
      int kc = idx / 324;
      int rem = idx - kc * 324;
      int r = rem / 18, col = rem - r * 18;
      int ih = th0 + r - 1, iw = tw0 + col - 1;
      float v = 0.f;
      if (ih >= 0 && ih < H && iw >= 0 && iw < W)
        v = gb[(size_t)(c0 + kc) * H * W + (size_t)ih * W + iw];
      xs[kc][r][col] = v;
    }
    __syncthreads();
#pragma unroll
    for (int kc = 0; kc < KCC; ++kc) {
      float xc = xs[kc][pr + 1][pc + 1];
#pragma unroll
      for (int di = 0; di < 3; ++di)
#pragma unroll
        for (int dj = 0; dj < 3; ++dj) {
          float d = xs[kc][pr + di][pc + dj] - xc;
          acc[di * 3 + dj] = fmaf(d, d, acc[di * 3 + dj]);
        }
    }
    __syncthreads();
  }

  size_t base = (size_t)b * 9 * H * W + (size_t)(th0 + pr) * W + tw0 + pc;
#pragma unroll
  for (int t = 0; t < 9; ++t) {
    size_t a = base + (size_t)t * H * W;
    if (CS > 1) atomicAdd(&s[a], acc[t]);
    else        s[a] = acc[t];
  }
}

// stage 2: k = exp(-0.5 * coeff^2 * s)
__global__ __launch_bounds__(256) void pac_s2(
    const float* __restrict__ s, float* __restrict__ k, float c2, int n)
{
  int i = blockIdx.x * 256 + threadIdx.x;
  if (i < n) k[i] = expf(-0.5f * c2 * s[i]);
}

// epilogue for c-split convs: out = relu(partial + bias[c])
__global__ __launch_bounds__(256) void bias_relu_k(
    const float* __restrict__ p, const float* __restrict__ bias,
    float* __restrict__ out, int C, int HW, int n)
{
  int i = blockIdx.x * 256 + threadIdx.x;
  if (i < n) {
    int c = (i / HW) % C;
    out[i] = fmaxf(p[i] + bias[c], 0.f);
  }
}

// weight transpose: [Cout][Cin][3][3] -> [Cin][9][Cout], all 14 layers
struct TPack {
  const float* src[14];
  float* dst[14];
  int ci[14];
  int co[14];
};

__global__ __launch_bounds__(256) void transpose_w(TPack p)
{
  for (int l = 0; l < 14; ++l) {
    const int ci = p.ci[l], co = p.co[l];
    const int n = ci * co * 9;
    const float* s = p.src[l];
    float* d = p.dst[l];
    for (int idx = blockIdx.x * 256 + threadIdx.x; idx < n;
         idx += gridDim.x * 256) {
      int c = idx / (9 * co);
      int rem = idx - c * 9 * co;
      int t = rem / co;
      int oc = rem - t * co;
      d[idx] = s[((size_t)oc * ci + c) * 9 + t];
    }
  }
}

// ---------------------------------------------------------------------------
// host-side dispatch
// ---------------------------------------------------------------------------
static void launch_conv(hipStream_t st, const float* src, const float* w, int wmode,
                        const float* bias, const float* kern, float* dst,
                        int Cin, int Cout, int H, int S, int HK, int SP, int CS)
{
  const int OH = H / S, OW = H / S;
  dim3 grid((OH / 8) * (OW / 16), Cout / 64, 2 * CS);
  dim3 blk(256);
  if (S == 1 && !HK && !SP) {
    if (Cin == 1)
      conv3x3_k<1,0,0,1><<<grid, blk, 0, st>>>(src, w, wmode, bias, kern, dst, Cin, Cout, H, H, CS);
    else
      conv3x3_k<1,0,0,8><<<grid, blk, 0, st>>>(src, w, wmode, bias, kern, dst, Cin, Cout, H, H, CS);
  } else if (S == 2 && !HK && !SP) {
    conv3x3_k<2,0,0,4><<<grid, blk, 0, st>>>(src, w, wmode, bias, kern, dst, Cin, Cout, H, H, CS);
  } else if (S == 1 && HK && !SP) {
    conv3x3_k<1,1,0,8><<<grid, blk, 0, st>>>(src, w, wmode, bias, kern, dst, Cin, Cout, H, H, CS);
  } else if (S == 1 && HK && SP) {
    conv3x3_k<1,1,1,8><<<grid, blk, 0, st>>>(src, w, wmode, bias, kern, dst, Cin, Cout, H, H, CS);
  } else { // S == 2 && HK && SP
    conv3x3_k<2,1,1,4><<<grid, blk, 0, st>>>(src, w, wmode, bias, kern, dst, Cin, Cout, H, H, CS);
  }
}

extern "C" void kernel_launch(void* const* d_in, const int* in_sizes, int n_in,
                              void* d_out, int out_size, void* d_ws, size_t ws_size,
                              hipStream_t stream)
{
  (void)in_sizes; (void)n_in; (void)out_size;
  const float* x = (const float*)d_in[0];
  const float* Wp[14];
  const float* Bp[14];
  for (int l = 0; l < 14; ++l) {
    Wp[l] = (const float*)d_in[1 + 2 * l];
    Bp[l] = (const float*)d_in[2 + 2 * l];
  }
  float* out = (float*)d_out;
  float* ws  = (float*)d_ws;

  float* A  = ws + OFF_A;
  float* Bf = ws + OFF_B;
  float* P  = ws + OFF_P;
  float* Pk = ws + OFF_PK;
  float* WT = ws + OFF_WT;

  const int ci[14] = {1,64,64, 64,128,128, 128,256,256, 256,512,512, 512,1024};
  const int co[14] = {64,64,64, 128,128,128, 256,256,256, 512,512,512, 1024,1024};

  const int wmode = (ws_size >= (size_t)WS_FULL_FLOATS * 4) ? 1 : 0;

  // per-layer weight pointer (transposed if it fits, raw otherwise)
  const float* wl[14];
  if (wmode) {
    size_t off = 0;
    TPack tp;
    for (int l = 0; l < 14; ++l) {
      tp.src[l] = Wp[l];
      tp.dst[l] = WT + off;
      tp.ci[l] = ci[l];
      tp.co[l] = co[l];
      wl[l] = WT + off;
      off += (size_t)ci[l] * co[l] * 9;
    }
    transpose_w<<<2048, 256, 0, stream>>>(tp);
  } else {
    for (int l = 0; l < 14; ++l) wl[l] = Wp[l];
  }

  float* h1 = out + O_H1;
  float* h2 = out + O_H2;
  float* h3 = out + O_H3;
  float* h4 = out + O_H4;
  float* h5 = out + O_H5;
  float* k2 = out + O_K2;
  float* k3 = out + O_K3;
  float* k4 = out + O_K4;
  float* k5 = out + O_K5;

  // ---- stage 1: plain convs ----
  // 1_1: x[2,1,256,256] -> A[2,64,256,256]
  launch_conv(stream, x,  wl[0], wmode, Bp[0], nullptr, A,  1,  64, 256, 1, 0, 0, 1);
  // 1_2: A -> h1
  launch_conv(stream, A,  wl[1], wmode, Bp[1], nullptr, h1, 64, 64, 256, 1, 0, 0, 1);
  // 1_3: h1 -> Bf[2,64,128,128], stride 2
  launch_conv(stream, h1, wl[2], wmode, Bp[2], nullptr, Bf, 64, 64, 256, 2, 0, 0, 1);

  // ---- k2 = pac_kernel(Bf * 1e-4) : [2,9,128,128] ----
  {
    dim3 g((128 / 16) * (128 / 16), 2);
    pac_s1<4><<<g, 256, 0, stream>>>(Bf, Pk, 64, 128, 128, 1);
    int n = 2 * 9 * 128 * 128;
    pac_s2<<<(n + 255) / 256, 256, 0, stream>>>(Pk, k2, 1e-8f, n);
  }

  // 2_1: Bf -> A[2,128,128,128]  (PAC k2)
  launch_conv(stream, Bf, wl[3], wmode, Bp[3], k2, A,  64, 128, 128, 1, 1, 0, 1);
  // 2_2: A -> h2 (PAC k2)
  launch_conv(stream, A,  wl[4], wmode, Bp[4], k2, h2, 128, 128, 128, 1, 1, 0, 1);
  // 2_3: h2 -> P (split CS=2, PAC k2 strided) ; epi -> Bf[2,128,64,64]
  {
    int n = 2 * 128 * 64 * 64;
    hipMemsetAsync(P, 0, (size_t)n * 4, stream);
    launch_conv(stream, h2, wl[5], wmode, Bp[5], k2, P, 128, 128, 128, 2, 1, 1, 2);
    bias_relu_k<<<(n + 255) / 256, 256, 0, stream>>>(P, Bp[5], Bf, 128, 64 * 64, n);
  }

  // ---- k3 : [2,9,64,64] ----
  {
    dim3 g((64 / 16) * (64 / 16), 2);
    pac_s1<4><<<g, 256, 0, stream>>>(Bf, Pk, 128, 64, 64, 1);
    int n = 2 * 9 * 64 * 64;
    pac_s2<<<(n + 255) / 256, 256, 0, stream>>>(Pk, k3, 1e-8f, n);
  }

  // 3_1: Bf -> A[2,256,64,64] (PAC k3)
  launch_conv(stream, Bf, wl[6], wmode, Bp[6], k3, A,  128, 256, 64, 1, 1, 0, 1);
  // 3_2: A -> h3 (PAC k3)
  launch_conv(stream, A,  wl[7], wmode, Bp[7], k3, h3, 256, 256, 64, 1, 1, 0, 1);
  // 3_3: h3 -> P (split CS=4) ; epi -> Bf[2,256,32,32]
  {
    int n = 2 * 256 * 32 * 32;
    hipMemsetAsync(P, 0, (size_t)n * 4, stream);
    launch_conv(stream, h3, wl[8], wmode, Bp[8], k3, P, 256, 256, 64, 2, 1, 1, 4);
    bias_relu_k<<<(n + 255) / 256, 256, 0, stream>>>(P, Bp[8], Bf, 256, 32 * 32, n);
  }

  // ---- k4 : [2,9,32,32], coeff 2.0 -> c2 = 4 ----
  {
    int n = 2 * 9 * 32 * 32;
    hipMemsetAsync(Pk, 0, (size_t)n * 4, stream);
    dim3 g((32 / 16) * (32 / 16), 2 * 4);
    pac_s1<4><<<g, 256, 0, stream>>>(Bf, Pk, 256, 32, 32, 4);
    pac_s2<<<(n + 255) / 256, 256, 0, stream>>>(Pk, k4, 4.0f, n);
  }

  // 4_1: Bf -> P (split CS=2) ; epi -> A[2,512,32,32]
  {
    int n = 2 * 512 * 32 * 32;
    hipMemsetAsync(P, 0, (size_t)n * 4, stream);
    launch_conv(stream, Bf, wl[9], wmode, Bp[9], k4, P, 256, 512, 32, 1, 1, 1, 2);
    bias_relu_k<<<(n + 255) / 256, 256, 0, stream>>>(P, Bp[9], A, 512, 32 * 32, n);
  }
  // 4_2: A -> P (split CS=2) ; epi -> h4
  {
    int n = 2 * 512 * 32 * 32;
    hipMemsetAsync(P, 0, (size_t)n * 4, stream);
    launch_conv(stream, A, wl[10], wmode, Bp[10], k4, P, 512, 512, 32, 1, 1, 1, 2);
    bias_relu_k<<<(n + 255) / 256, 256, 0, stream>>>(P, Bp[10], h4, 512, 32 * 32, n);
  }
  // 4_3: h4 -> P (split CS=8, stride 2) ; epi -> Bf[2,512,16,16]
  {
    int n = 2 * 512 * 16 * 16;
    hipMemsetAsync(P, 0, (size_t)n * 4, stream);
    launch_conv(stream, h4, wl[11], wmode, Bp[11], k4, P, 512, 512, 32, 2, 1, 1, 8);
    bias_relu_k<<<(n + 255) / 256, 256, 0, stream>>>(P, Bp[11], Bf, 512, 16 * 16, n);
  }

  // ---- k5 : [2,9,16,16] ----
  {
    int n = 2 * 9 * 16 * 16;
    hipMemsetAsync(Pk, 0, (size_t)n * 4, stream);
    dim3 g(1, 2 * 8);
    pac_s1<4><<<g, 256, 0, stream>>>(Bf, Pk, 512, 16, 16, 8);
    pac_s2<<<(n + 255) / 256, 256, 0, stream>>>(Pk, k5, 1e-8f, n);
  }

  // 5_1: Bf -> P (split CS=4) ; epi -> A[2,1024,16,16]
  {
    int n = 2 * 1024 * 16 * 16;
    hipMemsetAsync(P, 0, (size_t)n * 4, stream);
    launch_conv(stream, Bf, wl[12], wmode, Bp[12], k5, P, 512, 1024, 16, 1, 1, 1, 4);
    bias_relu_k<<<(n + 255) / 256, 256, 0, stream>>>(P, Bp[12], A, 1024, 16 * 16, n);
  }
  // 5_2: A -> P (split CS=4) ; epi -> h5
  {
    int n = 2 * 1024 * 16 * 16;
    hipMemsetAsync(P, 0, (size_t)n * 4, stream);
    launch_conv(stream, A, wl[13], wmode, Bp[13], k5, P, 1024, 1024, 16, 1, 1, 1, 4);
    bias_relu_k<<<(n + 255) / 256, 256, 0, stream>>>(P, Bp[13], h5, 1024, 16 * 16, n);
  }
}